// Round 1
// baseline (550.357 us; speedup 1.0000x reference)
//
#include <hip/hip_runtime.h>
#include <math.h>

#define HH 512
#define WW 512
#define NB 64
#define HW (HH*WW)

struct GaussK { float k[13]; };

__device__ __forceinline__ float idenv(int i) {
    // identity grid coordinate: (2*i - 511)/511
    return (float)(2*i - (WW-1)) / (float)(WW-1);
}

#define DEF_OFF ((float)((2.0 + 4.0/511.0)/2.0))
#define BOUND   ((float)(2.0/512.0*8.0))

// ---------------- vertical blur of prim channel 0 -> out plane 0 ----------------
__global__ void k_vblur(const float* __restrict__ prim, float* __restrict__ out, GaussK gk) {
    int idx = blockIdx.x*256 + threadIdx.x;          // over B*H*W
    int w = idx & (WW-1);
    int h = (idx >> 9) & (HH-1);
    int b = idx >> 18;
    const float* src = prim + (size_t)b*2*HW;        // channel 0
    float acc = 0.f;
    #pragma unroll
    for (int i = 0; i < 13; ++i) {
        int hh = h - 6 + i;
        hh = hh < 0 ? -hh : (hh > HH-1 ? 2*(HH-1) - hh : hh);   // reflect
        acc = fmaf(gk.k[i], src[(size_t)hh*WW + w], acc);
    }
    out[(size_t)b*3*HW + (size_t)h*WW + w] = acc;    // plane 0
}

// ---------------- horizontal blur of prim channel 1 -> out plane 1 ----------------
__global__ void k_hblur(const float* __restrict__ prim, float* __restrict__ out, GaussK gk) {
    int idx = blockIdx.x*256 + threadIdx.x;
    int w = idx & (WW-1);
    int h = (idx >> 9) & (HH-1);
    int b = idx >> 18;
    const float* src = prim + ((size_t)b*2 + 1)*HW + (size_t)h*WW;  // channel 1, row h
    float acc = 0.f;
    #pragma unroll
    for (int i = 0; i < 13; ++i) {
        int x = w - 6 + i;
        x = x < 0 ? -x : (x > WW-1 ? 2*(WW-1) - x : x);
        acc = fmaf(gk.k[i], src[x], acc);
    }
    out[((size_t)b*3 + 1)*HW + (size_t)h*WW + w] = acc;             // plane 1
}

// ---- fused horizontal blur + row scan (x channel), in-place on plane 0 ----
// one wave (64 threads) per (b,h) row; lane l owns columns 8l..8l+7
__global__ void k_xscan(float* __restrict__ out, GaussK gk) {
    __shared__ float row[WW + 12];   // row[j] = vblur value at column (j-6), reflected
    int b = blockIdx.x >> 9;
    int h = blockIdx.x & (HH-1);
    float* plane0 = out + (size_t)b*3*HW + (size_t)h*WW;
    int lane = threadIdx.x;

    for (int j = lane; j < WW + 12; j += 64) {
        int x = j - 6;
        x = x < 0 ? -x : (x > WW-1 ? 2*(WW-1) - x : x);
        row[j] = plane0[x];
    }
    __syncthreads();

    // s values for columns 8l-1 .. 8l+7 (9 values); col -1 -> s = 0 (prepend zero)
    float s[9];
    int base = lane*8 - 1;
    #pragma unroll
    for (int j = 0; j < 9; ++j) {
        int wcol = base + j;
        float v = 0.f;
        if (wcol >= 0) {
            float acc = 0.f;
            #pragma unroll
            for (int i = 0; i < 13; ++i) acc = fmaf(gk.k[i], row[wcol + i], acc);
            v = acc + idenv(wcol) + DEF_OFF;
        }
        s[j] = v;
    }
    // local relu'd diffs + prefix
    float qs[8];
    float q = 0.f;
    #pragma unroll
    for (int j = 1; j < 9; ++j) {
        q += fmaxf(s[j] - s[j-1], 0.f);
        qs[j-1] = q;
    }
    // wave inclusive scan of per-lane totals
    float inc = q;
    #pragma unroll
    for (int d = 1; d < 64; d <<= 1) {
        float t = __shfl_up(inc, d, 64);
        if (lane >= d) inc += t;
    }
    float excl = inc - q;

    #pragma unroll
    for (int j = 0; j < 8; ++j) {
        int wcol = lane*8 + j;
        float sx = excl + qs[j];
        float p = sx - DEF_OFF - idenv(wcol);
        p = fminf(fmaxf(p, -BOUND), BOUND);
        float g = p + idenv(wcol);
        g = fminf(fmaxf(g, -1.f), 1.f);
        plane0[wcol] = g;   // safe: whole row already staged to LDS by this wave
    }
}

// ---- fused vertical blur + column scan (y channel): read plane 1, write plane 2 ----
// one thread per (b, w) column, rolling 13-row register window
__global__ void k_yscan(float* __restrict__ out, GaussK gk) {
    int idx = blockIdx.x*256 + threadIdx.x;   // over B*W
    int w = idx & (WW-1);
    int b = idx >> 9;
    const float* p1 = out + ((size_t)b*3 + 1)*HW;   // hblur(ch1), read-only here
    float*       p2 = out + ((size_t)b*3 + 2)*HW;   // grid-y destination

    float win[13];
    #pragma unroll
    for (int i = 0; i < 13; ++i) {
        int r = i - 6;
        r = r < 0 ? -r : r;                 // reflect top
        win[i] = p1[(size_t)r*WW + w];
    }
    float sprev = 0.f, run = 0.f;
    for (int h = 0; h < HH; ++h) {
        if (h > 0) {
            #pragma unroll
            for (int i = 0; i < 12; ++i) win[i] = win[i+1];
            int r = h + 6;
            if (r > HH-1) r = 2*(HH-1) - r; // reflect bottom (plane1 is never modified)
            win[12] = p1[(size_t)r*WW + w];
        }
        float acc = 0.f;
        #pragma unroll
        for (int i = 0; i < 13; ++i) acc = fmaf(gk.k[i], win[i], acc);
        float s = acc + idenv(h) + DEF_OFF;
        run += fmaxf(s - sprev, 0.f);
        sprev = s;
        float p = run - DEF_OFF - idenv(h);
        p = fminf(fmaxf(p, -BOUND), BOUND);
        float g = p + idenv(h);
        g = fminf(fmaxf(g, -1.f), 1.f);
        p2[(size_t)h*WW + w] = g;
    }
}

// ---- bilinear grid sample: grid-x from plane 0, grid-y from plane 2 ----
// overwrites all 3 planes (element-exclusive read-then-write per thread)
__global__ void k_sample(const float* __restrict__ image, float* __restrict__ out) {
    int idx = blockIdx.x*256 + threadIdx.x;   // over B*H*W
    int w = idx & (WW-1);
    int h = (idx >> 9) & (HH-1);
    int b = idx >> 18;
    float* ob = out + (size_t)b*3*HW;
    size_t off = (size_t)h*WW + w;
    float gx = ob[off];            // plane 0
    float gy = ob[2*HW + off];     // plane 2
    float fx = (gx + 1.f) * 0.5f * (float)(WW-1);
    float fy = (gy + 1.f) * 0.5f * (float)(HH-1);
    float x0f = floorf(fx), y0f = floorf(fy);
    float wx = fx - x0f, wy = fy - y0f;
    int x0 = (int)x0f, y0 = (int)y0f;          // in [0, 511] since grid clipped to [-1,1]
    int x1 = x0 + 1; if (x1 > WW-1) x1 = WW-1; // wx==0 there, so clamp is exact
    int y1 = y0 + 1; if (y1 > HH-1) y1 = HH-1;
    const float* ib = image + (size_t)b*3*HW;
    float w00 = (1.f-wx)*(1.f-wy), w01 = wx*(1.f-wy), w10 = (1.f-wx)*wy, w11 = wx*wy;
    #pragma unroll
    for (int c = 0; c < 3; ++c) {
        const float* ip = ib + (size_t)c*HW;
        float v00 = ip[(size_t)y0*WW + x0];
        float v01 = ip[(size_t)y0*WW + x1];
        float v10 = ip[(size_t)y1*WW + x0];
        float v11 = ip[(size_t)y1*WW + x1];
        float v = v00*w00 + v01*w01 + v10*w10 + v11*w11;
        ob[(size_t)c*HW + off] = v;
    }
}

extern "C" void kernel_launch(void* const* d_in, const int* in_sizes, int n_in,
                              void* d_out, int out_size, void* d_ws, size_t ws_size,
                              hipStream_t stream) {
    const float* image = (const float*)d_in[0];
    const float* prim  = (const float*)d_in[1];
    float* out = (float*)d_out;

    GaussK gk;
    {
        double sigma = 13.0*0.15 + 0.35;   // 2.3
        double pdf[13], sum = 0.0;
        for (int i = 0; i < 13; ++i) {
            double t = (double)(i - 6);
            pdf[i] = exp(-0.5*(t/sigma)*(t/sigma));
            sum += pdf[i];
        }
        for (int i = 0; i < 13; ++i) gk.k[i] = (float)(pdf[i]/sum);
    }

    int nElem = NB*HH*WW;                 // 16,777,216
    k_vblur <<<nElem/256, 256, 0, stream>>>(prim, out, gk);
    k_hblur <<<nElem/256, 256, 0, stream>>>(prim, out, gk);
    k_xscan <<<NB*HH,      64, 0, stream>>>(out, gk);
    k_yscan <<<NB*WW/256, 256, 0, stream>>>(out, gk);
    k_sample<<<nElem/256, 256, 0, stream>>>(image, out);
}

// Round 2
// 370.840 us; speedup vs baseline: 1.4841x; 1.4841x over previous
//
#include <hip/hip_runtime.h>
#include <math.h>

#define HH 512
#define WW 512
#define NB 64
#define HW (HH*WW)

struct GaussK { float k[13]; };

__device__ __forceinline__ float idenv(int i) {
    return (float)(2*i - (WW-1)) / (float)(WW-1);
}

#define DEF_OFF ((float)((2.0 + 4.0/511.0)/2.0))
#define BOUND   ((float)(2.0/512.0*8.0))

// ---------------- vertical blur of prim channel 0 -> out plane 0 ----------------
__global__ void k_vblur(const float* __restrict__ prim, float* __restrict__ out, GaussK gk) {
    int idx = blockIdx.x*256 + threadIdx.x;          // over B*H*W
    int w = idx & (WW-1);
    int h = (idx >> 9) & (HH-1);
    int b = idx >> 18;
    const float* src = prim + (size_t)b*2*HW;        // channel 0
    float acc = 0.f;
    #pragma unroll
    for (int i = 0; i < 13; ++i) {
        int hh = h - 6 + i;
        hh = hh < 0 ? -hh : (hh > HH-1 ? 2*(HH-1) - hh : hh);   // reflect
        acc = fmaf(gk.k[i], src[(size_t)hh*WW + w], acc);
    }
    out[(size_t)b*3*HW + (size_t)h*WW + w] = acc;    // plane 0
}

// ---------------- horizontal blur of prim channel 1 -> out plane 1 ----------------
__global__ void k_hblur(const float* __restrict__ prim, float* __restrict__ out, GaussK gk) {
    int idx = blockIdx.x*256 + threadIdx.x;
    int w = idx & (WW-1);
    int h = (idx >> 9) & (HH-1);
    int b = idx >> 18;
    const float* src = prim + ((size_t)b*2 + 1)*HW + (size_t)h*WW;  // channel 1, row h
    float acc = 0.f;
    #pragma unroll
    for (int i = 0; i < 13; ++i) {
        int x = w - 6 + i;
        x = x < 0 ? -x : (x > WW-1 ? 2*(WW-1) - x : x);
        acc = fmaf(gk.k[i], src[x], acc);
    }
    out[((size_t)b*3 + 1)*HW + (size_t)h*WW + w] = acc;             // plane 1
}

// ---- fused horizontal blur + row scan (x channel), in-place on plane 0 ----
// one wave (64 threads) per (b,h) row; lane l owns columns 8l..8l+7
__global__ void k_xscan(float* __restrict__ out, GaussK gk) {
    __shared__ float row[WW + 12];   // row[j] = vblur value at column (j-6), reflected
    int b = blockIdx.x >> 9;
    int h = blockIdx.x & (HH-1);
    float* plane0 = out + (size_t)b*3*HW + (size_t)h*WW;
    int lane = threadIdx.x;

    for (int j = lane; j < WW + 12; j += 64) {
        int x = j - 6;
        x = x < 0 ? -x : (x > WW-1 ? 2*(WW-1) - x : x);
        row[j] = plane0[x];
    }
    __syncthreads();

    float s[9];
    int base = lane*8 - 1;
    #pragma unroll
    for (int j = 0; j < 9; ++j) {
        int wcol = base + j;
        float v = 0.f;
        if (wcol >= 0) {
            float acc = 0.f;
            #pragma unroll
            for (int i = 0; i < 13; ++i) acc = fmaf(gk.k[i], row[wcol + i], acc);
            v = acc + idenv(wcol) + DEF_OFF;
        }
        s[j] = v;
    }
    float qs[8];
    float q = 0.f;
    #pragma unroll
    for (int j = 1; j < 9; ++j) {
        q += fmaxf(s[j] - s[j-1], 0.f);
        qs[j-1] = q;
    }
    float inc = q;
    #pragma unroll
    for (int d = 1; d < 64; d <<= 1) {
        float t = __shfl_up(inc, d, 64);
        if (lane >= d) inc += t;
    }
    float excl = inc - q;

    #pragma unroll
    for (int j = 0; j < 8; ++j) {
        int wcol = lane*8 + j;
        float sx = excl + qs[j];
        float p = sx - DEF_OFF - idenv(wcol);
        p = fminf(fmaxf(p, -BOUND), BOUND);
        float g = p + idenv(wcol);
        g = fminf(fmaxf(g, -1.f), 1.f);
        plane0[wcol] = g;
    }
}

// ---- fused vertical blur + column scan (y channel): read plane 1, write plane 2 ----
// Segmented: block = 512 threads = 8 waves; wave ws owns rows [ws*64, ws*64+64)
// for 64 consecutive columns (lane = column). Pass1 partials -> LDS prefix -> pass2.
__global__ void __launch_bounds__(512) k_yscan(float* __restrict__ out, GaussK gk) {
    __shared__ float segsum[8][64];
    int b    = blockIdx.x >> 3;          // 64*8 = 512 blocks
    int wt   = blockIdx.x & 7;
    int lane = threadIdx.x & 63;
    int ws   = threadIdx.x >> 6;
    int w    = wt*64 + lane;
    const float* p1 = out + ((size_t)b*3 + 1)*HW + w;   // hblur(ch1), read-only
    float*       p2 = out + ((size_t)b*3 + 2)*HW + w;   // grid-y destination
    int r0 = ws*64;

    #define LDROW(r_) ({ int r = (r_); r = r < 0 ? -r : (r > HH-1 ? 2*(HH-1) - r : r); \
                         p1[(size_t)r*WW]; })

    // ---------- pass 1: per-segment partial sum ----------
    float qsum = 0.f;
    {
        float win[13], sprev;
        int h;
        if (ws == 0) {
            #pragma unroll
            for (int i = 0; i < 13; ++i) win[i] = LDROW(-6 + i);
            sprev = 0.f; h = 0;
        } else {
            #pragma unroll
            for (int i = 0; i < 13; ++i) win[i] = LDROW(r0 - 7 + i);
            float acc = 0.f;
            #pragma unroll
            for (int i = 0; i < 13; ++i) acc = fmaf(gk.k[i], win[i], acc);
            sprev = acc + idenv(r0 - 1) + DEF_OFF;
            #pragma unroll
            for (int i = 0; i < 12; ++i) win[i] = win[i+1];
            win[12] = LDROW(r0 + 6);
            h = r0;
        }
        for (int n = 0; n < 64; ++n) {
            float acc = 0.f;
            #pragma unroll
            for (int i = 0; i < 13; ++i) acc = fmaf(gk.k[i], win[i], acc);
            float s = acc + idenv(h) + DEF_OFF;
            qsum += fmaxf(s - sprev, 0.f);
            sprev = s;
            ++h;
            if (n < 63) {
                #pragma unroll
                for (int i = 0; i < 12; ++i) win[i] = win[i+1];
                win[12] = LDROW(h + 6);
            }
        }
    }
    segsum[ws][lane] = qsum;
    __syncthreads();
    float run = 0.f;
    for (int k = 0; k < ws; ++k) run += segsum[k][lane];

    // ---------- pass 2: recompute + write ----------
    {
        float win[13], sprev;
        int h;
        if (ws == 0) {
            #pragma unroll
            for (int i = 0; i < 13; ++i) win[i] = LDROW(-6 + i);
            sprev = 0.f; h = 0;
        } else {
            #pragma unroll
            for (int i = 0; i < 13; ++i) win[i] = LDROW(r0 - 7 + i);
            float acc = 0.f;
            #pragma unroll
            for (int i = 0; i < 13; ++i) acc = fmaf(gk.k[i], win[i], acc);
            sprev = acc + idenv(r0 - 1) + DEF_OFF;
            #pragma unroll
            for (int i = 0; i < 12; ++i) win[i] = win[i+1];
            win[12] = LDROW(r0 + 6);
            h = r0;
        }
        for (int n = 0; n < 64; ++n) {
            float acc = 0.f;
            #pragma unroll
            for (int i = 0; i < 13; ++i) acc = fmaf(gk.k[i], win[i], acc);
            float s = acc + idenv(h) + DEF_OFF;
            run += fmaxf(s - sprev, 0.f);
            sprev = s;
            float p = run - DEF_OFF - idenv(h);
            p = fminf(fmaxf(p, -BOUND), BOUND);
            float g = p + idenv(h);
            g = fminf(fmaxf(g, -1.f), 1.f);
            p2[(size_t)h*WW] = g;
            ++h;
            if (n < 63) {
                #pragma unroll
                for (int i = 0; i < 12; ++i) win[i] = win[i+1];
                win[12] = LDROW(h + 6);
            }
        }
    }
    #undef LDROW
}

// ---- bilinear grid sample: grid-x from plane 0, grid-y from plane 2 ----
__global__ void k_sample(const float* __restrict__ image, float* __restrict__ out) {
    int idx = blockIdx.x*256 + threadIdx.x;   // over B*H*W
    int w = idx & (WW-1);
    int h = (idx >> 9) & (HH-1);
    int b = idx >> 18;
    float* ob = out + (size_t)b*3*HW;
    size_t off = (size_t)h*WW + w;
    float gx = ob[off];            // plane 0
    float gy = ob[2*HW + off];     // plane 2
    float fx = (gx + 1.f) * 0.5f * (float)(WW-1);
    float fy = (gy + 1.f) * 0.5f * (float)(HH-1);
    float x0f = floorf(fx), y0f = floorf(fy);
    float wx = fx - x0f, wy = fy - y0f;
    int x0 = (int)x0f, y0 = (int)y0f;
    int x1 = x0 + 1; if (x1 > WW-1) x1 = WW-1;
    int y1 = y0 + 1; if (y1 > HH-1) y1 = HH-1;
    const float* ib = image + (size_t)b*3*HW;
    float w00 = (1.f-wx)*(1.f-wy), w01 = wx*(1.f-wy), w10 = (1.f-wx)*wy, w11 = wx*wy;
    #pragma unroll
    for (int c = 0; c < 3; ++c) {
        const float* ip = ib + (size_t)c*HW;
        float v00 = ip[(size_t)y0*WW + x0];
        float v01 = ip[(size_t)y0*WW + x1];
        float v10 = ip[(size_t)y1*WW + x0];
        float v11 = ip[(size_t)y1*WW + x1];
        float v = v00*w00 + v01*w01 + v10*w10 + v11*w11;
        ob[(size_t)c*HW + off] = v;
    }
}

extern "C" void kernel_launch(void* const* d_in, const int* in_sizes, int n_in,
                              void* d_out, int out_size, void* d_ws, size_t ws_size,
                              hipStream_t stream) {
    const float* image = (const float*)d_in[0];
    const float* prim  = (const float*)d_in[1];
    float* out = (float*)d_out;

    GaussK gk;
    {
        double sigma = 13.0*0.15 + 0.35;   // 2.3
        double pdf[13], sum = 0.0;
        for (int i = 0; i < 13; ++i) {
            double t = (double)(i - 6);
            pdf[i] = exp(-0.5*(t/sigma)*(t/sigma));
            sum += pdf[i];
        }
        for (int i = 0; i < 13; ++i) gk.k[i] = (float)(pdf[i]/sum);
    }

    int nElem = NB*HH*WW;                 // 16,777,216
    k_vblur <<<nElem/256, 256, 0, stream>>>(prim, out, gk);
    k_hblur <<<nElem/256, 256, 0, stream>>>(prim, out, gk);
    k_xscan <<<NB*HH,      64, 0, stream>>>(out, gk);
    k_yscan <<<NB*8,      512, 0, stream>>>(out, gk);
    k_sample<<<nElem/256, 256, 0, stream>>>(image, out);
}